// Round 8
// baseline (271.467 us; speedup 1.0000x reference)
//
#include <hip/hip_runtime.h>
#include <hip/hip_bf16.h>
#include <math.h>

typedef __bf16 bf16;
typedef __attribute__((ext_vector_type(8))) __bf16 bf16x8;
typedef __attribute__((ext_vector_type(4))) __bf16 bf16x4;
typedef __attribute__((ext_vector_type(4))) float floatx4;

#define BB 2
#define NN 2048
#define LL 2048
#define DD 1024
#define HH 16
#define HDD 64

// Q pre-scale: HD^-0.5 * log2(e) -> scores come out of QK^T in log2 units
#define QSCALE (0.125f * 1.44269504f)
#define PCLAMP 21.66f
#define MBIAS  (-100000.0f)

// async global->LDS, 16B per lane. LDS dest must be wave-uniform + lane*16.
__device__ __forceinline__ void async16(const bf16* g, bf16* l) {
  __builtin_amdgcn_global_load_lds((const __attribute__((address_space(1))) void*)(g),
                                   (__attribute__((address_space(3))) void*)(l), 16, 0, 0);
}

// ---------------------------------------------------------------------------
// pad_mask dtype detector (int32 {0,1} / packed bool bytes / float32 {0,1}).
// ---------------------------------------------------------------------------
__global__ void detect_mask_kernel(const unsigned* __restrict__ m, int* __restrict__ flag) {
  __shared__ int hasBig, hasFloat;
  if (threadIdx.x == 0) { hasBig = 0; hasFloat = 0; }
  __syncthreads();
  int big = 0, flt = 0;
  for (int idx = threadIdx.x; idx < 1024; idx += 256) {
    unsigned v = m[idx];
    if (v == 0x3F800000u) flt = 1;
    else if (v > 1u) big = 1;
  }
  if (big) atomicOr(&hasBig, 1);
  if (flt) atomicOr(&hasFloat, 1);
  __syncthreads();
  if (threadIdx.x == 0) *flag = hasFloat ? 2 : (hasBig ? 1 : 0);
}

// ---------------------------------------------------------------------------
// f32 -> bf16 elementwise convert, 8 elems/thread.
// ---------------------------------------------------------------------------
__global__ __launch_bounds__(256) void convert_kernel(
    const float* __restrict__ src, bf16* __restrict__ dst, int n)
{
  int idx = (blockIdx.x * 256 + threadIdx.x) * 8;
  if (idx >= n) return;
  floatx4 a = *(const floatx4*)&src[idx];
  floatx4 b = *(const floatx4*)&src[idx + 4];
  bf16x8 o;
#pragma unroll
  for (int e = 0; e < 4; e++) { o[e] = (bf16)a[e]; o[4 + e] = (bf16)b[e]; }
  *(bf16x8*)&dst[idx] = o;
}

// ---------------------------------------------------------------------------
// W[1024][1024] f32 -> Wt[1024][1024] bf16 transposed ([n][k]).
// ---------------------------------------------------------------------------
__global__ __launch_bounds__(256) void wtrans_kernel(
    const float* __restrict__ W0, const float* __restrict__ W1,
    const float* __restrict__ W2, const float* __restrict__ W3,
    bf16* __restrict__ T0, bf16* __restrict__ T1,
    bf16* __restrict__ T2, bf16* __restrict__ T3)
{
  __shared__ bf16 Tb[64][72];
  const int bid = blockIdx.x;
  const int which = bid >> 8;
  const float* W = which == 0 ? W0 : which == 1 ? W1 : which == 2 ? W2 : W3;
  bf16*       T = which == 0 ? T0 : which == 1 ? T1 : which == 2 ? T2 : T3;
  const int tile = bid & 255;
  const int k0 = (tile >> 4) * 64, n0 = (tile & 15) * 64;
  const int t = threadIdx.x;
  const int r = t >> 2;
  const int c = (t & 3) * 16;
  const float* Wr = W + (size_t)(k0 + r) * 1024 + n0 + c;
  floatx4 f0 = *(const floatx4*)(Wr + 0);
  floatx4 f1 = *(const floatx4*)(Wr + 4);
  floatx4 f2 = *(const floatx4*)(Wr + 8);
  floatx4 f3 = *(const floatx4*)(Wr + 12);
#pragma unroll
  for (int e = 0; e < 4; e++) {
    Tb[c + e][r]      = (bf16)f0[e];
    Tb[c + 4 + e][r]  = (bf16)f1[e];
    Tb[c + 8 + e][r]  = (bf16)f2[e];
    Tb[c + 12 + e][r] = (bf16)f3[e];
  }
  __syncthreads();
  bf16* Tr = T + (size_t)(n0 + r) * 1024 + k0 + c;
  *(bf16x8*)&Tr[0] = *(const bf16x8*)&Tb[r][c];
  *(bf16x8*)&Tr[8] = *(const bf16x8*)&Tb[r][c + 8];
}

// ---------------------------------------------------------------------------
// GEMM body, m97-style 128x128 tile, BK=64. C = (A @ Wt^T + bias) * scale.
// 4 waves 2x2; wave = 64x64 = 4x4 MFMAs. N fixed at 1024 -> 8 col tiles.
// transv: write bf16 V^T globally as Vt[b][col][key].
// ---------------------------------------------------------------------------
template <typename TC>
__device__ __forceinline__ void gemm_body(
    int bx, const bf16* __restrict__ A, const bf16* __restrict__ Wt,
    const float* __restrict__ bias, TC* __restrict__ C, float scale, int transv)
{
  __shared__ bf16 As[128 * 64];
  __shared__ bf16 Bs[128 * 64];

  const int tm = bx >> 3, tn = bx & 7;
  const int m0 = tm * 128, n0 = tn * 128;
  const int t = threadIdx.x;
  const int w = t >> 6, l = t & 63;
  const int q = l >> 4, i = l & 15;
  const int wm = (w >> 1) * 64, wn = (w & 1) * 64;
  const int sr = t >> 3;           // 0..31
  const int sc = (t & 7) * 8;      // 0..56

  const floatx4 zero = {0.f, 0.f, 0.f, 0.f};
  floatx4 acc[4][4];
#pragma unroll
  for (int mi = 0; mi < 4; mi++)
#pragma unroll
    for (int ni = 0; ni < 4; ni++) acc[mi][ni] = zero;

  for (int k0 = 0; k0 < 1024; k0 += 64) {
    __syncthreads();
#pragma unroll
    for (int j = 0; j < 4; j++)
      async16(&A[(size_t)(m0 + j * 32 + sr) * 1024 + k0 + sc], &As[(j * 32 + sr) * 64 + sc]);
#pragma unroll
    for (int j = 0; j < 4; j++)
      async16(&Wt[(size_t)(n0 + j * 32 + sr) * 1024 + k0 + sc], &Bs[(j * 32 + sr) * 64 + sc]);
    __syncthreads();
#pragma unroll
    for (int ks = 0; ks < 2; ks++) {
      bf16x8 af[4], bfr[4];
#pragma unroll
      for (int mi = 0; mi < 4; mi++)
        af[mi] = *(const bf16x8*)&As[(wm + mi * 16 + i) * 64 + ks * 32 + q * 8];
#pragma unroll
      for (int ni = 0; ni < 4; ni++)
        bfr[ni] = *(const bf16x8*)&Bs[(wn + ni * 16 + i) * 64 + ks * 32 + q * 8];
#pragma unroll
      for (int mi = 0; mi < 4; mi++)
#pragma unroll
        for (int ni = 0; ni < 4; ni++)
          acc[mi][ni] = __builtin_amdgcn_mfma_f32_16x16x32_bf16(af[mi], bfr[ni], acc[mi][ni], 0, 0, 0);
    }
  }
#pragma unroll
  for (int ni = 0; ni < 4; ni++) {
    int col = n0 + wn + ni * 16 + i;
    float bv = bias[col];
#pragma unroll
    for (int mi = 0; mi < 4; mi++) {
      int row = m0 + wm + mi * 16 + q * 4;
      if (transv) {
        int bb = row >> 11, key = row & 2047;
        bf16x4 v4;
#pragma unroll
        for (int r = 0; r < 4; r++) v4[r] = (bf16)(acc[mi][ni][r] + bv);
        *(bf16x4*)&((bf16*)C)[(size_t)bb * (DD * (size_t)LL) + (size_t)col * LL + key] = v4;
      } else {
#pragma unroll
        for (int r = 0; r < 4; r++)
          C[(size_t)(row + r) * 1024 + col] = (TC)((acc[mi][ni][r] + bv) * scale);
      }
    }
  }
}

// Fused Q/K/V projection: grid = 3 << shift; which = bid >> shift.
__global__ __launch_bounds__(256) void qkv_gemm(
    const bf16* __restrict__ Xq, const bf16* __restrict__ Xkv,
    const bf16* __restrict__ Wtq, const bf16* __restrict__ Wtk, const bf16* __restrict__ Wtv,
    const float* __restrict__ bq, const float* __restrict__ bk, const float* __restrict__ bv,
    bf16* __restrict__ Qp, bf16* __restrict__ Kp, bf16* __restrict__ VtG, int shift)
{
  const int bid = blockIdx.x;
  const int which = bid >> shift;
  const int bx = bid & ((1 << shift) - 1);
  if (which == 0)      gemm_body<bf16>(bx, Xq,  Wtq, bq, Qp,  QSCALE, 0);
  else if (which == 1) gemm_body<bf16>(bx, Xkv, Wtk, bk, Kp,  1.0f,   0);
  else                 gemm_body<bf16>(bx, Xkv, Wtv, bv, VtG, 1.0f,   1);
}

__global__ __launch_bounds__(256) void out_gemm(
    const bf16* __restrict__ A, const bf16* __restrict__ Wt,
    const float* __restrict__ bias, float* __restrict__ C)
{
  gemm_body<float>(blockIdx.x, A, Wt, bias, C, 1.0f, 0);
}

// ---------------------------------------------------------------------------
// Flash attention v3: block = (b, h, 128-qrow tile), 4 waves x 32 qrows.
// Each wave holds TWO 16-qrow groups; kf/vf/bias LDS reads shared across
// both (2x MFMA per staged byte vs v2). S^T formulation, fixed-max softmax,
// mask bias via MFMA acc init, scores in log2 units.
// ---------------------------------------------------------------------------
__global__ __launch_bounds__(256) void attn_kernel(
    const bf16* __restrict__ Q, const bf16* __restrict__ K,
    const bf16* __restrict__ Vt, const void* __restrict__ mask,
    const int* __restrict__ flag, bf16* __restrict__ O, int mbase)
{
  __shared__ bf16 Ks[64][72];        // [key][d]
  __shared__ bf16 Vs[64][72];        // [d][key]  (from global V^T)
  __shared__ bf16 Ps[4][32][72];     // per-wave P^T as [qrow][key]
  __shared__ float biasL[2048];      // 0 or MBIAS per key

  const int bid = blockIdx.x;
  const int qt = bid & 15;           // 16 q-tiles of 128
  const int h  = (bid >> 4) & 15;
  const int b  = bid >> 8;
  const int t = threadIdx.x;
  const int w = t >> 6, lane = t & 63;
  const int q = lane >> 4, i = lane & 15;

  const int mode = *flag;
  const int mb = mbase + b;
  {
    const int base = t * 8;
    if (mode == 0) {
      const int* mm = ((const int*)mask) + mb * LL + base;
#pragma unroll
      for (int e = 0; e < 8; e++) biasL[base + e] = mm[e] ? MBIAS : 0.0f;
    } else if (mode == 1) {
      const unsigned char* mm = ((const unsigned char*)mask) + mb * LL + base;
#pragma unroll
      for (int e = 0; e < 8; e++) biasL[base + e] = mm[e] ? MBIAS : 0.0f;
    } else {
      const float* mm = ((const float*)mask) + mb * LL + base;
#pragma unroll
      for (int e = 0; e < 8; e++) biasL[base + e] = (mm[e] != 0.0f) ? MBIAS : 0.0f;
    }
  }

  const bf16* Qb = Q  + (size_t)b * (NN * DD) + h * HDD;
  const bf16* Kb = K  + (size_t)b * (LL * DD) + h * HDD;
  const bf16* Vb = Vt + (size_t)b * (DD * (size_t)LL) + (size_t)(h * HDD) * LL;

  const int qrow = qt * 128 + w * 32;   // wave's rows: qrow + g*16 + i
  bf16x8 qfrag[2][2];
#pragma unroll
  for (int g = 0; g < 2; g++)
#pragma unroll
    for (int ks = 0; ks < 2; ks++)
      qfrag[g][ks] = *(const bf16x8*)&Qb[(size_t)(qrow + g * 16 + i) * DD + ks * 32 + q * 8];

  const floatx4 zero = {0.f, 0.f, 0.f, 0.f};
  floatx4 oacc[2][4];
#pragma unroll
  for (int g = 0; g < 2; g++)
#pragma unroll
    for (int n = 0; n < 4; n++) oacc[g][n] = zero;
  float psum[2] = {0.f, 0.f};

  const int ldr = t >> 3;          // 0..31
  const int ldc = (t & 7) * 8;     // 0..56

  for (int kt = 0; kt < LL; kt += 64) {
    __syncthreads();
    *(bf16x8*)&Ks[ldr][ldc]      = *(const bf16x8*)&Kb[(size_t)(kt + ldr) * DD + ldc];
    *(bf16x8*)&Ks[ldr + 32][ldc] = *(const bf16x8*)&Kb[(size_t)(kt + ldr + 32) * DD + ldc];
    *(bf16x8*)&Vs[ldr][ldc]      = *(const bf16x8*)&Vb[(size_t)ldr * LL + kt + ldc];
    *(bf16x8*)&Vs[ldr + 32][ldc] = *(const bf16x8*)&Vb[(size_t)(ldr + 32) * LL + kt + ldc];
    __syncthreads();

    // S^T[key][qrow] = K·Q^T + maskbias; kf + bias shared across g
#pragma unroll
    for (int n = 0; n < 4; n++) {
      bf16x8 kf0 = *(const bf16x8*)&Ks[n * 16 + i][q * 8];
      bf16x8 kf1 = *(const bf16x8*)&Ks[n * 16 + i][32 + q * 8];
      floatx4 bv = *(const floatx4*)&biasL[kt + n * 16 + q * 4];
#pragma unroll
      for (int g = 0; g < 2; g++) {
        floatx4 a = __builtin_amdgcn_mfma_f32_16x16x32_bf16(kf0, qfrag[g][0], bv, 0, 0, 0);
        a = __builtin_amdgcn_mfma_f32_16x16x32_bf16(kf1, qfrag[g][1], a, 0, 0, 0);
        bf16x4 v4;
#pragma unroll
        for (int r = 0; r < 4; r++) {
          float p = __builtin_amdgcn_exp2f(fminf(a[r], PCLAMP));
          psum[g] += p;
          v4[r] = (bf16)p;
        }
        *(bf16x4*)&Ps[w][g * 16 + i][n * 16 + q * 4] = v4;
      }
    }
    // per-wave Ps buffer: DS pipe is in-order per wave; no barrier needed
    bf16x8 pf[2][2];
#pragma unroll
    for (int g = 0; g < 2; g++)
#pragma unroll
      for (int ks = 0; ks < 2; ks++)
        pf[g][ks] = *(const bf16x8*)&Ps[w][g * 16 + i][ks * 32 + q * 8];
    // O^T += V^T · P^T; vf shared across g
#pragma unroll
    for (int n = 0; n < 4; n++) {
      bf16x8 vf0 = *(const bf16x8*)&Vs[n * 16 + i][q * 8];
      bf16x8 vf1 = *(const bf16x8*)&Vs[n * 16 + i][32 + q * 8];
#pragma unroll
      for (int g = 0; g < 2; g++) {
        oacc[g][n] = __builtin_amdgcn_mfma_f32_16x16x32_bf16(vf0, pf[g][0], oacc[g][n], 0, 0, 0);
        oacc[g][n] = __builtin_amdgcn_mfma_f32_16x16x32_bf16(vf1, pf[g][1], oacc[g][n], 0, 0, 0);
      }
    }
  }

  bf16* Ob = O + (size_t)b * (NN * DD) + h * HDD;
#pragma unroll
  for (int g = 0; g < 2; g++) {
    float ps = psum[g];
    ps += __shfl_xor(ps, 16, 64);
    ps += __shfl_xor(ps, 32, 64);
    float inv = 1.0f / fmaxf(ps, 1e-30f);
    const size_t rbase = (size_t)(qrow + g * 16 + i) * DD;
#pragma unroll
    for (int n = 0; n < 4; n++) {
      bf16x4 v4;
#pragma unroll
      for (int r = 0; r < 4; r++) v4[r] = (bf16)(oacc[g][n][r] * inv);
      *(bf16x4*)&Ob[rbase + n * 16 + q * 4] = v4;
    }
  }
}

// ---------------------------------------------------------------------------
extern "C" void kernel_launch(void* const* d_in, const int* in_sizes, int n_in,
                              void* d_out, int out_size, void* d_ws, size_t ws_size,
                              hipStream_t stream)
{
  const float* x_q  = (const float*)d_in[0];
  const float* x_kv = (const float*)d_in[1];
  const void*  pad  = d_in[2];
  const float* wq = (const float*)d_in[3];
  const float* bq = (const float*)d_in[4];
  const float* wk = (const float*)d_in[5];
  const float* bk = (const float*)d_in[6];
  const float* wv = (const float*)d_in[7];
  const float* bv = (const float*)d_in[8];
  const float* wo = (const float*)d_in[9];
  const float* bo = (const float*)d_in[10];
  float* out = (float*)d_out;

  char* ws = (char*)d_ws;
  const size_t MB = (size_t)1 << 20;
  const size_t fullElems = (size_t)BB * NN * DD;  // 4M
  const size_t batchElems = (size_t)NN * DD;      // 2M

  int* flag = (int*)((char*)d_out + (size_t)out_size * sizeof(float) - 16);
  detect_mask_kernel<<<1, 256, 0, stream>>>((const unsigned*)pad, flag);

  if (ws_size >= 48 * MB) {
    bf16* Xqb  = (bf16*)(ws);            // 8 MB, reused as Op after Q-GEMM
    bf16* Xkvb = (bf16*)(ws + 8 * MB);
    bf16* Wtq  = (bf16*)(ws + 16 * MB);
    bf16* Wtk  = (bf16*)(ws + 18 * MB);
    bf16* Wtv  = (bf16*)(ws + 20 * MB);
    bf16* Wto  = (bf16*)(ws + 22 * MB);
    bf16* Qp   = (bf16*)(ws + 24 * MB);
    bf16* Kp   = (bf16*)(ws + 32 * MB);
    bf16* VtG  = (bf16*)(ws + 40 * MB);
    bf16* Op   = Xqb;

    convert_kernel<<<2048, 256, 0, stream>>>(x_q,  Xqb,  (int)fullElems);
    convert_kernel<<<2048, 256, 0, stream>>>(x_kv, Xkvb, (int)fullElems);
    wtrans_kernel<<<1024, 256, 0, stream>>>(wq, wk, wv, wo, Wtq, Wtk, Wtv, Wto);
    qkv_gemm<<<768, 256, 0, stream>>>(Xqb, Xkvb, Wtq, Wtk, Wtv, bq, bk, bv, Qp, Kp, VtG, 8);
    attn_kernel<<<512, 256, 0, stream>>>(Qp, Kp, VtG, pad, flag, Op, 0);
    out_gemm<<<256, 256, 0, stream>>>(Op, Wto, bo, out);
  } else {
    bf16* Wtq  = (bf16*)(ws);
    bf16* Wtk  = (bf16*)(ws + 2 * MB);
    bf16* Wtv  = (bf16*)(ws + 4 * MB);
    bf16* Wto  = (bf16*)(ws + 6 * MB);
    bf16* Xqb  = (bf16*)(ws + 8 * MB);   // 4 MB, reused as Op
    bf16* Xkvb = (bf16*)(ws + 12 * MB);
    bf16* Qp   = (bf16*)(ws + 16 * MB);
    bf16* Kp   = (bf16*)(ws + 20 * MB);
    bf16* VtG  = (bf16*)(ws + 24 * MB);
    bf16* Op   = Xqb;

    wtrans_kernel<<<1024, 256, 0, stream>>>(wq, wk, wv, wo, Wtq, Wtk, Wtv, Wto);
    for (int b = 0; b < BB; b++) {
      convert_kernel<<<1024, 256, 0, stream>>>(x_q  + b * batchElems, Xqb,  (int)batchElems);
      convert_kernel<<<1024, 256, 0, stream>>>(x_kv + b * batchElems, Xkvb, (int)batchElems);
      qkv_gemm<<<384, 256, 0, stream>>>(Xqb, Xkvb, Wtq, Wtk, Wtv, bq, bk, bv, Qp, Kp, VtG, 7);
      attn_kernel<<<256, 256, 0, stream>>>(Qp, Kp, VtG, pad, flag, Op, b);
      out_gemm<<<128, 256, 0, stream>>>(Op, Wto, bo, out + b * batchElems);
    }
  }
}

// Round 9
// 244.070 us; speedup vs baseline: 1.1123x; 1.1123x over previous
//
#include <hip/hip_runtime.h>
#include <hip/hip_bf16.h>
#include <math.h>

typedef __bf16 bf16;
typedef __attribute__((ext_vector_type(8))) __bf16 bf16x8;
typedef __attribute__((ext_vector_type(4))) __bf16 bf16x4;
typedef __attribute__((ext_vector_type(4))) float floatx4;

#define BB 2
#define NN 2048
#define LL 2048
#define DD 1024
#define HH 16
#define HDD 64

// Q pre-scale: HD^-0.5 * log2(e) -> scores come out of QK^T in log2 units
#define QSCALE (0.125f * 1.44269504f)
#define PCLAMP 21.66f
#define MBIAS  (-100000.0f)

// async global->LDS, 16B per lane. LDS dest must be wave-uniform + lane*16.
__device__ __forceinline__ void async16(const bf16* g, bf16* l) {
  __builtin_amdgcn_global_load_lds((const __attribute__((address_space(1))) void*)(g),
                                   (__attribute__((address_space(3))) void*)(l), 16, 0, 0);
}

// ---------------------------------------------------------------------------
// pad_mask dtype detector (int32 {0,1} / packed bool bytes / float32 {0,1}).
// ---------------------------------------------------------------------------
__global__ void detect_mask_kernel(const unsigned* __restrict__ m, int* __restrict__ flag) {
  __shared__ int hasBig, hasFloat;
  if (threadIdx.x == 0) { hasBig = 0; hasFloat = 0; }
  __syncthreads();
  int big = 0, flt = 0;
  for (int idx = threadIdx.x; idx < 1024; idx += 256) {
    unsigned v = m[idx];
    if (v == 0x3F800000u) flt = 1;
    else if (v > 1u) big = 1;
  }
  if (big) atomicOr(&hasBig, 1);
  if (flt) atomicOr(&hasFloat, 1);
  __syncthreads();
  if (threadIdx.x == 0) *flag = hasFloat ? 2 : (hasBig ? 1 : 0);
}

// ---------------------------------------------------------------------------
// Fused f32 -> bf16 convert for two buffers, 8 elems/thread.
// Blocks [0,nb) -> (srcA,dstA); [nb,2nb) -> (srcB,dstB).
// ---------------------------------------------------------------------------
__global__ __launch_bounds__(256) void convert2_kernel(
    const float* __restrict__ srcA, bf16* __restrict__ dstA,
    const float* __restrict__ srcB, bf16* __restrict__ dstB, int nb, int n)
{
  int gid = blockIdx.x;
  const float* s = srcA; bf16* d = dstA;
  if (gid >= nb) { s = srcB; d = dstB; gid -= nb; }
  int idx = (gid * 256 + threadIdx.x) * 8;
  if (idx >= n) return;
  floatx4 a = *(const floatx4*)&s[idx];
  floatx4 b = *(const floatx4*)&s[idx + 4];
  bf16x8 o;
#pragma unroll
  for (int e = 0; e < 4; e++) { o[e] = (bf16)a[e]; o[4 + e] = (bf16)b[e]; }
  *(bf16x8*)&d[idx] = o;
}

// ---------------------------------------------------------------------------
// W[1024][1024] f32 -> Wt[1024][1024] bf16 transposed ([n][k]).
// ---------------------------------------------------------------------------
__global__ __launch_bounds__(256) void wtrans_kernel(
    const float* __restrict__ W0, const float* __restrict__ W1,
    const float* __restrict__ W2, const float* __restrict__ W3,
    bf16* __restrict__ T0, bf16* __restrict__ T1,
    bf16* __restrict__ T2, bf16* __restrict__ T3)
{
  __shared__ bf16 Tb[64][72];
  const int bid = blockIdx.x;
  const int which = bid >> 8;
  const float* W = which == 0 ? W0 : which == 1 ? W1 : which == 2 ? W2 : W3;
  bf16*       T = which == 0 ? T0 : which == 1 ? T1 : which == 2 ? T2 : T3;
  const int tile = bid & 255;
  const int k0 = (tile >> 4) * 64, n0 = (tile & 15) * 64;
  const int t = threadIdx.x;
  const int r = t >> 2;
  const int c = (t & 3) * 16;
  const float* Wr = W + (size_t)(k0 + r) * 1024 + n0 + c;
  floatx4 f0 = *(const floatx4*)(Wr + 0);
  floatx4 f1 = *(const floatx4*)(Wr + 4);
  floatx4 f2 = *(const floatx4*)(Wr + 8);
  floatx4 f3 = *(const floatx4*)(Wr + 12);
#pragma unroll
  for (int e = 0; e < 4; e++) {
    Tb[c + e][r]      = (bf16)f0[e];
    Tb[c + 4 + e][r]  = (bf16)f1[e];
    Tb[c + 8 + e][r]  = (bf16)f2[e];
    Tb[c + 12 + e][r] = (bf16)f3[e];
  }
  __syncthreads();
  bf16* Tr = T + (size_t)(n0 + r) * 1024 + k0 + c;
  *(bf16x8*)&Tr[0] = *(const bf16x8*)&Tb[r][c];
  *(bf16x8*)&Tr[8] = *(const bf16x8*)&Tb[r][c + 8];
}

// ---------------------------------------------------------------------------
// GEMM body (round-7 proven): 128x64 tile, BK=64. C = (A @ Wt^T + bias)*scale.
// 4 waves 2x2; wave = 64x32 = 4x2 MFMAs. Staging via global_load_lds dwordx4.
// transv: write bf16 V^T globally as Vt[b][col][key].
// ---------------------------------------------------------------------------
template <typename TC>
__device__ __forceinline__ void gemm_body(
    int bx, const bf16* __restrict__ A, const bf16* __restrict__ Wt,
    const float* __restrict__ bias, TC* __restrict__ C, float scale, int transv)
{
  __shared__ bf16 As[128 * 64];
  __shared__ bf16 Bs[64 * 64];

  const int tm = bx >> 4, tn = bx & 15;
  const int m0 = tm * 128, n0 = tn * 64;
  const int t = threadIdx.x;
  const int w = t >> 6, l = t & 63;
  const int q = l >> 4, i = l & 15;
  const int wm = (w >> 1) * 64, wn = (w & 1) * 32;
  const int sr = t >> 3;
  const int sc = (t & 7) * 8;

  const floatx4 zero = {0.f, 0.f, 0.f, 0.f};
  floatx4 acc[4][2];
#pragma unroll
  for (int mi = 0; mi < 4; mi++)
#pragma unroll
    for (int ni = 0; ni < 2; ni++) acc[mi][ni] = zero;

  for (int k0 = 0; k0 < 1024; k0 += 64) {
    __syncthreads();
#pragma unroll
    for (int j = 0; j < 4; j++)
      async16(&A[(size_t)(m0 + j * 32 + sr) * 1024 + k0 + sc], &As[(j * 32 + sr) * 64 + sc]);
#pragma unroll
    for (int j = 0; j < 2; j++)
      async16(&Wt[(size_t)(n0 + j * 32 + sr) * 1024 + k0 + sc], &Bs[(j * 32 + sr) * 64 + sc]);
    __syncthreads();
#pragma unroll
    for (int ks = 0; ks < 2; ks++) {
      bf16x8 af[4], bfr[2];
#pragma unroll
      for (int mi = 0; mi < 4; mi++)
        af[mi] = *(const bf16x8*)&As[(wm + mi * 16 + i) * 64 + ks * 32 + q * 8];
#pragma unroll
      for (int ni = 0; ni < 2; ni++)
        bfr[ni] = *(const bf16x8*)&Bs[(wn + ni * 16 + i) * 64 + ks * 32 + q * 8];
#pragma unroll
      for (int mi = 0; mi < 4; mi++)
#pragma unroll
        for (int ni = 0; ni < 2; ni++)
          acc[mi][ni] = __builtin_amdgcn_mfma_f32_16x16x32_bf16(af[mi], bfr[ni], acc[mi][ni], 0, 0, 0);
    }
  }
#pragma unroll
  for (int ni = 0; ni < 2; ni++) {
    int col = n0 + wn + ni * 16 + i;
    float bv = bias[col];
#pragma unroll
    for (int mi = 0; mi < 4; mi++) {
      int row = m0 + wm + mi * 16 + q * 4;
      if (transv) {
        int bb = row >> 11, key = row & 2047;
        bf16x4 v4;
#pragma unroll
        for (int r = 0; r < 4; r++) v4[r] = (bf16)(acc[mi][ni][r] + bv);
        *(bf16x4*)&((bf16*)C)[(size_t)bb * (DD * (size_t)LL) + (size_t)col * LL + key] = v4;
      } else {
#pragma unroll
        for (int r = 0; r < 4; r++)
          C[(size_t)(row + r) * 1024 + col] = (TC)((acc[mi][ni][r] + bv) * scale);
      }
    }
  }
}

// Fused Q/K/V projection: grid = 3 << shift; which = bid >> shift.
__global__ __launch_bounds__(256) void qkv_gemm(
    const bf16* __restrict__ Xq, const bf16* __restrict__ Xkv,
    const bf16* __restrict__ Wtq, const bf16* __restrict__ Wtk, const bf16* __restrict__ Wtv,
    const float* __restrict__ bq, const float* __restrict__ bk, const float* __restrict__ bv,
    bf16* __restrict__ Qp, bf16* __restrict__ Kp, bf16* __restrict__ VtG, int shift)
{
  const int bid = blockIdx.x;
  const int which = bid >> shift;
  const int bx = bid & ((1 << shift) - 1);
  if (which == 0)      gemm_body<bf16>(bx, Xq,  Wtq, bq, Qp,  QSCALE, 0);
  else if (which == 1) gemm_body<bf16>(bx, Xkv, Wtk, bk, Kp,  1.0f,   0);
  else                 gemm_body<bf16>(bx, Xkv, Wtv, bv, VtG, 1.0f,   1);
}

__global__ __launch_bounds__(256) void out_gemm(
    const bf16* __restrict__ A, const bf16* __restrict__ Wt,
    const float* __restrict__ bias, float* __restrict__ C)
{
  gemm_body<float>(blockIdx.x, A, Wt, bias, C, 1.0f, 0);
}

// ---------------------------------------------------------------------------
// Flash attention v4 = v2 (round-7, 83 us) + register double-buffered K/V
// staging + XCD-aware block swizzle. Block = 64 qrows, 4 waves x 16 qrows.
// bid = qt<<hbits | hb; all 32 qt-tiles of one (h,b) share bid%8 -> same XCD
// L2 (K/V head slice = 1 MB working set per XCD). Next tile's K/V global
// loads are issued right after barrier-2 so their latency overlaps the
// MFMA+exp compute window. S^T formulation, fixed-max softmax, mask bias as
// MFMA acc init, scores in log2 units.
// ---------------------------------------------------------------------------
__global__ __launch_bounds__(256) void attn_kernel(
    const bf16* __restrict__ Q, const bf16* __restrict__ K,
    const bf16* __restrict__ Vt, const void* __restrict__ mask,
    const int* __restrict__ flag, bf16* __restrict__ O, int hbits, int mbase)
{
  __shared__ bf16 Ks[64][72];        // [key][d]
  __shared__ bf16 Vs[64][72];        // [d][key]  (from global V^T)
  __shared__ bf16 Ps[4][16][72];     // per-wave P^T as [qrow][key]
  __shared__ float biasL[2048];      // 0 or MBIAS per key

  const int bid = blockIdx.x;
  const int qt = bid >> hbits;
  const int hb = bid & ((1 << hbits) - 1);
  const int h  = (hbits == 5) ? (hb >> 1) : hb;
  const int b  = (hbits == 5) ? (hb & 1) : 0;
  const int t = threadIdx.x;
  const int w = t >> 6, lane = t & 63;
  const int q = lane >> 4, i = lane & 15;

  const int mode = *flag;
  const int mb = mbase + b;
  {
    const int base = t * 8;
    if (mode == 0) {
      const int* mm = ((const int*)mask) + mb * LL + base;
#pragma unroll
      for (int e = 0; e < 8; e++) biasL[base + e] = mm[e] ? MBIAS : 0.0f;
    } else if (mode == 1) {
      const unsigned char* mm = ((const unsigned char*)mask) + mb * LL + base;
#pragma unroll
      for (int e = 0; e < 8; e++) biasL[base + e] = mm[e] ? MBIAS : 0.0f;
    } else {
      const float* mm = ((const float*)mask) + mb * LL + base;
#pragma unroll
      for (int e = 0; e < 8; e++) biasL[base + e] = (mm[e] != 0.0f) ? MBIAS : 0.0f;
    }
  }

  const bf16* Qb = Q  + (size_t)b * (NN * DD) + h * HDD;
  const bf16* Kb = K  + (size_t)b * (LL * DD) + h * HDD;
  const bf16* Vb = Vt + (size_t)b * (DD * (size_t)LL) + (size_t)(h * HDD) * LL;

  const int qrow = qt * 64 + w * 16;
  bf16x8 qfrag[2];
#pragma unroll
  for (int ks = 0; ks < 2; ks++)
    qfrag[ks] = *(const bf16x8*)&Qb[(size_t)(qrow + i) * DD + ks * 32 + q * 8];

  const floatx4 zero = {0.f, 0.f, 0.f, 0.f};
  floatx4 oacc[4];                   // O^T[d = n*16+q*4+r][qrow = i]
#pragma unroll
  for (int n = 0; n < 4; n++) oacc[n] = zero;
  float psum = 0.0f;

  const int ldr = t >> 3;          // 0..31
  const int ldc = (t & 7) * 8;     // 0..56

  // preload tile 0 into registers
  bf16x8 pk0 = *(const bf16x8*)&Kb[(size_t)ldr * DD + ldc];
  bf16x8 pk1 = *(const bf16x8*)&Kb[(size_t)(ldr + 32) * DD + ldc];
  bf16x8 pv0 = *(const bf16x8*)&Vb[(size_t)ldr * LL + ldc];
  bf16x8 pv1 = *(const bf16x8*)&Vb[(size_t)(ldr + 32) * LL + ldc];

  for (int kt = 0; kt < LL; kt += 64) {
    __syncthreads();
    *(bf16x8*)&Ks[ldr][ldc]      = pk0;
    *(bf16x8*)&Ks[ldr + 32][ldc] = pk1;
    *(bf16x8*)&Vs[ldr][ldc]      = pv0;
    *(bf16x8*)&Vs[ldr + 32][ldc] = pv1;
    __syncthreads();

    // prefetch next tile (wraps on last iter; harmless L2 re-hit).
    // waitcnt for these sinks to next iteration's LDS writes -> latency
    // overlaps the compute below.
    {
      const int ktn = (kt + 64) & (LL - 1);
      pk0 = *(const bf16x8*)&Kb[(size_t)(ktn + ldr) * DD + ldc];
      pk1 = *(const bf16x8*)&Kb[(size_t)(ktn + ldr + 32) * DD + ldc];
      pv0 = *(const bf16x8*)&Vb[(size_t)ldr * LL + ktn + ldc];
      pv1 = *(const bf16x8*)&Vb[(size_t)(ldr + 32) * LL + ktn + ldc];
    }

    // S^T[key][qrow] = K·Q^T + maskbias  (contraction over d)
#pragma unroll
    for (int n = 0; n < 4; n++) {
      floatx4 bv = *(const floatx4*)&biasL[kt + n * 16 + q * 4];
      floatx4 a = bv;
#pragma unroll
      for (int ks = 0; ks < 2; ks++) {
        bf16x8 kf = *(const bf16x8*)&Ks[n * 16 + i][ks * 32 + q * 8];
        a = __builtin_amdgcn_mfma_f32_16x16x32_bf16(kf, qfrag[ks], a, 0, 0, 0);
      }
      bf16x4 v4;
#pragma unroll
      for (int r = 0; r < 4; r++) {
        float p = __builtin_amdgcn_exp2f(fminf(a[r], PCLAMP));
        psum += p;
        v4[r] = (bf16)p;
      }
      *(bf16x4*)&Ps[w][i][n * 16 + q * 4] = v4;
    }
    // per-wave Ps buffer: DS pipe in-order per wave; no barrier needed
    bf16x8 pf[2];
#pragma unroll
    for (int ks = 0; ks < 2; ks++)
      pf[ks] = *(const bf16x8*)&Ps[w][i][ks * 32 + q * 8];
    // O^T += V^T · P^T  (contraction over key)
#pragma unroll
    for (int n = 0; n < 4; n++) {
#pragma unroll
      for (int ks = 0; ks < 2; ks++) {
        bf16x8 vf = *(const bf16x8*)&Vs[n * 16 + i][ks * 32 + q * 8];
        oacc[n] = __builtin_amdgcn_mfma_f32_16x16x32_bf16(vf, pf[ks], oacc[n], 0, 0, 0);
      }
    }
  }

  psum += __shfl_xor(psum, 16, 64);
  psum += __shfl_xor(psum, 32, 64);
  float inv = 1.0f / fmaxf(psum, 1e-30f);

  bf16* Ob = O + (size_t)b * (NN * DD) + h * HDD;
#pragma unroll
  for (int n = 0; n < 4; n++) {
    bf16x4 v4;
#pragma unroll
    for (int r = 0; r < 4; r++) v4[r] = (bf16)(oacc[n][r] * inv);
    *(bf16x4*)&Ob[(size_t)(qrow + i) * DD + n * 16 + q * 4] = v4;
  }
}

// ---------------------------------------------------------------------------
extern "C" void kernel_launch(void* const* d_in, const int* in_sizes, int n_in,
                              void* d_out, int out_size, void* d_ws, size_t ws_size,
                              hipStream_t stream)
{
  const float* x_q  = (const float*)d_in[0];
  const float* x_kv = (const float*)d_in[1];
  const void*  pad  = d_in[2];
  const float* wq = (const float*)d_in[3];
  const float* bq = (const float*)d_in[4];
  const float* wk = (const float*)d_in[5];
  const float* bk = (const float*)d_in[6];
  const float* wv = (const float*)d_in[7];
  const float* bv = (const float*)d_in[8];
  const float* wo = (const float*)d_in[9];
  const float* bo = (const float*)d_in[10];
  float* out = (float*)d_out;

  char* ws = (char*)d_ws;
  const size_t MB = (size_t)1 << 20;
  const size_t fullElems = (size_t)BB * NN * DD;  // 4M
  const size_t batchElems = (size_t)NN * DD;      // 2M

  int* flag = (int*)((char*)d_out + (size_t)out_size * sizeof(float) - 16);
  detect_mask_kernel<<<1, 256, 0, stream>>>((const unsigned*)pad, flag);

  if (ws_size >= 48 * MB) {
    bf16* Xqb  = (bf16*)(ws);            // 8 MB, reused as Op after Q-GEMM
    bf16* Xkvb = (bf16*)(ws + 8 * MB);
    bf16* Wtq  = (bf16*)(ws + 16 * MB);
    bf16* Wtk  = (bf16*)(ws + 18 * MB);
    bf16* Wtv  = (bf16*)(ws + 20 * MB);
    bf16* Wto  = (bf16*)(ws + 22 * MB);
    bf16* Qp   = (bf16*)(ws + 24 * MB);
    bf16* Kp   = (bf16*)(ws + 32 * MB);
    bf16* VtG  = (bf16*)(ws + 40 * MB);
    bf16* Op   = Xqb;

    convert2_kernel<<<4096, 256, 0, stream>>>(x_q, Xqb, x_kv, Xkvb, 2048, (int)fullElems);
    wtrans_kernel<<<1024, 256, 0, stream>>>(wq, wk, wv, wo, Wtq, Wtk, Wtv, Wto);
    qkv_gemm<<<1536, 256, 0, stream>>>(Xqb, Xkvb, Wtq, Wtk, Wtv, bq, bk, bv, Qp, Kp, VtG, 9);
    attn_kernel<<<1024, 256, 0, stream>>>(Qp, Kp, VtG, pad, flag, Op, 5, 0);
    out_gemm<<<512, 256, 0, stream>>>(Op, Wto, bo, out);
  } else {
    bf16* Wtq  = (bf16*)(ws);
    bf16* Wtk  = (bf16*)(ws + 2 * MB);
    bf16* Wtv  = (bf16*)(ws + 4 * MB);
    bf16* Wto  = (bf16*)(ws + 6 * MB);
    bf16* Xqb  = (bf16*)(ws + 8 * MB);   // 4 MB, reused as Op
    bf16* Xkvb = (bf16*)(ws + 12 * MB);
    bf16* Qp   = (bf16*)(ws + 16 * MB);
    bf16* Kp   = (bf16*)(ws + 20 * MB);
    bf16* VtG  = (bf16*)(ws + 24 * MB);
    bf16* Op   = Xqb;

    wtrans_kernel<<<1024, 256, 0, stream>>>(wq, wk, wv, wo, Wtq, Wtk, Wtv, Wto);
    for (int b = 0; b < BB; b++) {
      convert2_kernel<<<2048, 256, 0, stream>>>(x_q + b * batchElems, Xqb,
                                                x_kv + b * batchElems, Xkvb,
                                                1024, (int)batchElems);
      qkv_gemm<<<768, 256, 0, stream>>>(Xqb, Xkvb, Wtq, Wtk, Wtv, bq, bk, bv, Qp, Kp, VtG, 8);
      attn_kernel<<<512, 256, 0, stream>>>(Qp, Kp, VtG, pad, flag, Op, 4, b);
      out_gemm<<<256, 256, 0, stream>>>(Op, Wto, bo, out + b * batchElems);
    }
  }
}